// Round 1
// baseline (1073.371 us; speedup 1.0000x reference)
//
#include <hip/hip_runtime.h>
#include <math.h>

constexpr int NN = 200000;
constexpr int EE = 6400000;
constexpr int NB = (NN + 255) / 256;   // 782 blocks of 256
constexpr int U_ = 200000, T_ = 20000, C_ = 5000, G_ = 10000;

__device__ __forceinline__ int clampi(int v, int lo, int hi){ return v < lo ? lo : (v > hi ? hi : v); }
__device__ __forceinline__ float reluf(float v){ return v > 0.f ? v : 0.f; }

// ---- CSR build ----------------------------------------------------------

__global__ void k_count(const int* __restrict__ edges, int* __restrict__ count){
  int stride = gridDim.x * blockDim.x;
  for (int e = blockIdx.x * blockDim.x + threadIdx.x; e < EE; e += stride)
    atomicAdd(&count[edges[EE + e]], 1);          // col = edges[1][e]
}

__global__ void k_blocksum(const int* __restrict__ count, int* __restrict__ bsum){
  __shared__ int sb[256];
  int i = blockIdx.x * 256 + threadIdx.x;
  sb[threadIdx.x] = (i < NN) ? count[i] : 0;
  __syncthreads();
  for (int d = 128; d > 0; d >>= 1){
    if ((int)threadIdx.x < d) sb[threadIdx.x] += sb[threadIdx.x + d];
    __syncthreads();
  }
  if (threadIdx.x == 0) bsum[blockIdx.x] = sb[0];
}

__global__ void k_scanb(int* __restrict__ bsum){   // one block, 1024 threads; NB=782 fits
  __shared__ int s[1024];
  int t = threadIdx.x;
  int v = (t < NB) ? bsum[t] : 0;
  s[t] = v; __syncthreads();
  for (int d = 1; d < 1024; d <<= 1){
    int u = (t >= d) ? s[t - d] : 0;
    __syncthreads();
    s[t] += u;
    __syncthreads();
  }
  if (t < NB) bsum[t] = s[t] - v;                  // exclusive
}

__global__ void k_offsets(const int* __restrict__ count, const int* __restrict__ bsum,
                          int* __restrict__ off, int* __restrict__ cursor,
                          double* __restrict__ dis){
  __shared__ int sc[256];
  int tid = threadIdx.x;
  int i = blockIdx.x * 256 + tid;
  int v = (i < NN) ? count[i] : 0;
  sc[tid] = v; __syncthreads();
  for (int d = 1; d < 256; d <<= 1){
    int u = (tid >= d) ? sc[tid - d] : 0;
    __syncthreads();
    sc[tid] += u;
    __syncthreads();
  }
  if (i < NN){
    int st = bsum[blockIdx.x] + sc[tid] - v;       // global exclusive prefix
    off[i] = st;
    cursor[i] = st;
    dis[i] = 1.0 / sqrt((double)(v + 1));          // deg includes self-loop
  }
}

__global__ void k_fill(const int* __restrict__ edges, int* __restrict__ cursor,
                       int* __restrict__ srow){
  int stride = gridDim.x * blockDim.x;
  for (int e = blockIdx.x * blockDim.x + threadIdx.x; e < EE; e += stride){
    int c = edges[EE + e];
    int p = atomicAdd(&cursor[c], 1);
    srow[p] = edges[e];                            // row = edges[0][e]
  }
}

// ---- feature assembly + layer-1 pre-scale -------------------------------
// hs1[i][k] = dis[i] * (x_i @ W0)[k]   (16 floats/node)

__global__ void k_assemble(
    const int* __restrict__ features, const int* __restrict__ lmask,
    const float* __restrict__ user_emb, const float* __restrict__ known_emb,
    const float* __restrict__ mask_emb, const float* __restrict__ cat_emb,
    const float* __restrict__ topic_emb, const float* __restrict__ group_emb,
    const float* __restrict__ user_W, const float* __restrict__ user_b,
    const float* __restrict__ mask_W, const float* __restrict__ mask_b,
    const float* __restrict__ cat_W, const float* __restrict__ cat_b,
    const float* __restrict__ topic_W, const float* __restrict__ topic_b,
    const float* __restrict__ group_W, const float* __restrict__ group_b,
    const float* __restrict__ W0, const double* __restrict__ dis,
    float* __restrict__ hs1)
{
  __shared__ float s_userW[64], s_topicW[64], s_groupW[64], s_maskW[64];
  __shared__ float s_catW[16], s_knownE[16], s_maskE[16];
  __shared__ float s_W0[128];
  __shared__ float s_userb[8], s_topicb[8], s_catb[8], s_groupb[8], s_maskb[8];
  int tid = threadIdx.x;
  if (tid < 64){ s_userW[tid]=user_W[tid]; s_topicW[tid]=topic_W[tid];
                 s_groupW[tid]=group_W[tid]; s_maskW[tid]=mask_W[tid]; }
  if (tid < 16){ s_catW[tid]=cat_W[tid]; s_knownE[tid]=known_emb[tid]; s_maskE[tid]=mask_emb[tid]; }
  if (tid < 128) s_W0[tid]=W0[tid];
  if (tid < 8){ s_userb[tid]=user_b[tid]; s_topicb[tid]=topic_b[tid]; s_catb[tid]=cat_b[tid];
                s_groupb[tid]=group_b[tid]; s_maskb[tid]=mask_b[tid]; }
  __syncthreads();

  int i = blockIdx.x * 256 + tid;
  if (i >= NN) return;

  int idx   = features[3*i + 0];
  int known = features[3*i + 1];
  int tc    = features[3*i + 2];

  double x[8];
  #pragma unroll
  for (int k = 0; k < 8; k++) x[k] = 0.0;

  if (tc == 0){
    int id = clampi(idx, 0, U_-1);
    int kn = clampi(known, 0, 1);
    float a[8];
    #pragma unroll
    for (int d = 0; d < 8; d++) a[d] = reluf(user_emb[(size_t)id*8 + d] + s_knownE[kn*8 + d]);
    #pragma unroll
    for (int k = 0; k < 8; k++){
      double s = (double)s_userb[k];
      #pragma unroll
      for (int d = 0; d < 8; d++) s += (double)a[d] * (double)s_userW[d*8 + k];
      x[k] = s;
    }
  } else if (tc == 1){
    int id = clampi(idx, 0, T_-1);
    float a[8];
    #pragma unroll
    for (int d = 0; d < 8; d++) a[d] = reluf(topic_emb[(size_t)id*8 + d]);
    #pragma unroll
    for (int k = 0; k < 8; k++){
      double s = (double)s_topicb[k];
      #pragma unroll
      for (int d = 0; d < 8; d++) s += (double)a[d] * (double)s_topicW[d*8 + k];
      x[k] = s;
    }
  } else if (tc == 2){
    int id = clampi(idx, 0, C_-1);
    float a0 = reluf(cat_emb[(size_t)id*2 + 0]);
    float a1 = reluf(cat_emb[(size_t)id*2 + 1]);
    #pragma unroll
    for (int k = 0; k < 8; k++)
      x[k] = (double)s_catb[k] + (double)a0*(double)s_catW[k] + (double)a1*(double)s_catW[8 + k];
  } else if (tc == 4){
    int id = clampi(idx, 0, G_-1);
    float a[8];
    #pragma unroll
    for (int d = 0; d < 8; d++) a[d] = reluf(group_emb[(size_t)id*8 + d]);
    #pragma unroll
    for (int k = 0; k < 8; k++){
      double s = (double)s_groupb[k];
      #pragma unroll
      for (int d = 0; d < 8; d++) s += (double)a[d] * (double)s_groupW[d*8 + k];
      x[k] = s;
    }
  } // else: x stays 0 (tcode 3 unused)

  int m = clampi(lmask[i], 0, 1);
  float me[8];
  #pragma unroll
  for (int d = 0; d < 8; d++) me[d] = reluf(s_maskE[m*8 + d]);
  #pragma unroll
  for (int k = 0; k < 8; k++){
    double s = (double)s_maskb[k];
    #pragma unroll
    for (int d = 0; d < 8; d++) s += (double)me[d] * (double)s_maskW[d*8 + k];
    double mf = 1.0 / (1.0 + exp(-s));
    x[k] *= mf;
  }

  double di = dis[i];
  float h[16];
  #pragma unroll
  for (int j = 0; j < 16; j++){
    double s = 0.0;
    #pragma unroll
    for (int c = 0; c < 8; c++) s += x[c] * (double)s_W0[c*16 + j];
    h[j] = (float)(di * s);
  }
  float4* hp = (float4*)(hs1 + (size_t)i * 16);
  hp[0] = make_float4(h[0],  h[1],  h[2],  h[3]);
  hp[1] = make_float4(h[4],  h[5],  h[6],  h[7]);
  hp[2] = make_float4(h[8],  h[9],  h[10], h[11]);
  hp[3] = make_float4(h[12], h[13], h[14], h[15]);
}

// ---- layer 1 aggregation + relu + layer-2 pre-scale ----------------------
// out1[i] = relu(dis[i]*sum + b0); h2s[i] = dis[i] * (out1 @ W2)

__global__ void k_agg1(const float* __restrict__ hs1, const int* __restrict__ srow,
                       const int* __restrict__ off, const int* __restrict__ count,
                       const double* __restrict__ dis, const float* __restrict__ b0,
                       const float* __restrict__ W2, float* __restrict__ h2s)
{
  __shared__ float sb0[16], sW2[16];
  if (threadIdx.x < 16){ sb0[threadIdx.x] = b0[threadIdx.x]; sW2[threadIdx.x] = W2[threadIdx.x]; }
  __syncthreads();
  int i = blockIdx.x * 256 + threadIdx.x;
  if (i >= NN) return;

  const float4* hp = (const float4*)hs1;
  double acc[16];
  {
    float4 v0 = hp[i*4+0], v1 = hp[i*4+1], v2 = hp[i*4+2], v3 = hp[i*4+3]; // self-loop
    acc[0]=v0.x; acc[1]=v0.y; acc[2]=v0.z; acc[3]=v0.w;
    acc[4]=v1.x; acc[5]=v1.y; acc[6]=v1.z; acc[7]=v1.w;
    acc[8]=v2.x; acc[9]=v2.y; acc[10]=v2.z; acc[11]=v2.w;
    acc[12]=v3.x; acc[13]=v3.y; acc[14]=v3.z; acc[15]=v3.w;
  }
  int s = off[i], c = count[i];
  #pragma unroll 2
  for (int j = 0; j < c; j++){
    int r = srow[s + j];
    float4 v0 = hp[r*4+0], v1 = hp[r*4+1], v2 = hp[r*4+2], v3 = hp[r*4+3];
    acc[0]+=v0.x; acc[1]+=v0.y; acc[2]+=v0.z; acc[3]+=v0.w;
    acc[4]+=v1.x; acc[5]+=v1.y; acc[6]+=v1.z; acc[7]+=v1.w;
    acc[8]+=v2.x; acc[9]+=v2.y; acc[10]+=v2.z; acc[11]+=v2.w;
    acc[12]+=v3.x; acc[13]+=v3.y; acc[14]+=v3.z; acc[15]+=v3.w;
  }
  double di = dis[i];
  double h2 = 0.0;
  #pragma unroll
  for (int k = 0; k < 16; k++){
    double t = di * acc[k] + (double)sb0[k];
    double x2 = t > 0.0 ? t : 0.0;                 // relu
    h2 += x2 * (double)sW2[k];
  }
  h2s[i] = (float)(di * h2);
}

// ---- layer 2 aggregation + bias -----------------------------------------

__global__ void k_agg2(const float* __restrict__ h2s, const int* __restrict__ srow,
                       const int* __restrict__ off, const int* __restrict__ count,
                       const double* __restrict__ dis, const float* __restrict__ b2,
                       float* __restrict__ out)
{
  int i = blockIdx.x * 256 + threadIdx.x;
  if (i >= NN) return;
  double acc = (double)h2s[i];                     // self-loop
  int s = off[i], c = count[i];
  #pragma unroll 4
  for (int j = 0; j < c; j++)
    acc += (double)h2s[srow[s + j]];
  out[i] = (float)(dis[i] * acc + (double)b2[0]);
}

// ---- launch --------------------------------------------------------------

extern "C" void kernel_launch(void* const* d_in, const int* in_sizes, int n_in,
                              void* d_out, int out_size, void* d_ws, size_t ws_size,
                              hipStream_t stream)
{
  const int*   edges      = (const int*)  d_in[0];
  const int*   features   = (const int*)  d_in[1];
  const int*   label_mask = (const int*)  d_in[2];
  const float* user_emb   = (const float*)d_in[3];
  const float* known_emb  = (const float*)d_in[4];
  const float* mask_emb   = (const float*)d_in[5];
  const float* cat_emb    = (const float*)d_in[6];
  const float* topic_emb  = (const float*)d_in[7];
  const float* group_emb  = (const float*)d_in[8];
  const float* user_W     = (const float*)d_in[9];
  const float* user_b     = (const float*)d_in[10];
  const float* mask_W     = (const float*)d_in[11];
  const float* mask_b     = (const float*)d_in[12];
  const float* cat_W      = (const float*)d_in[13];
  const float* cat_b      = (const float*)d_in[14];
  const float* topic_W    = (const float*)d_in[15];
  const float* topic_b    = (const float*)d_in[16];
  const float* group_W    = (const float*)d_in[17];
  const float* group_b    = (const float*)d_in[18];
  const float* W0         = (const float*)d_in[19];
  const float* b0         = (const float*)d_in[20];
  const float* W2         = (const float*)d_in[21];
  const float* b2         = (const float*)d_in[22];
  float* out = (float*)d_out;

  char* ws = (char*)d_ws;
  size_t o = 0;
  auto alloc = [&](size_t bytes){ void* p = ws + o; o += (bytes + 255) & ~255ull; return p; };
  int*    count  = (int*)   alloc((size_t)NN * 4);
  int*    off    = (int*)   alloc((size_t)NN * 4);
  int*    cursor = (int*)   alloc((size_t)NN * 4);
  int*    bsum   = (int*)   alloc((size_t)NB * 4);
  double* dis    = (double*)alloc((size_t)NN * 8);
  int*    srow   = (int*)   alloc((size_t)EE * 4);
  float*  hs1    = (float*) alloc((size_t)NN * 16 * 4);
  float*  h2s    = (float*) alloc((size_t)NN * 4);
  // total ~44 MB of ws

  hipMemsetAsync(count, 0, (size_t)NN * 4, stream);
  k_count   <<<4096, 256, 0, stream>>>(edges, count);
  k_blocksum<<<NB,   256, 0, stream>>>(count, bsum);
  k_scanb   <<<1,   1024, 0, stream>>>(bsum);
  k_offsets <<<NB,   256, 0, stream>>>(count, bsum, off, cursor, dis);
  k_fill    <<<4096, 256, 0, stream>>>(edges, cursor, srow);
  k_assemble<<<NB,   256, 0, stream>>>(features, label_mask,
      user_emb, known_emb, mask_emb, cat_emb, topic_emb, group_emb,
      user_W, user_b, mask_W, mask_b, cat_W, cat_b,
      topic_W, topic_b, group_W, group_b, W0, dis, hs1);
  k_agg1    <<<NB,   256, 0, stream>>>(hs1, srow, off, count, dis, b0, W2, h2s);
  k_agg2    <<<NB,   256, 0, stream>>>(h2s, srow, off, count, dis, b2, out);
}